// Round 3
// baseline (127.130 us; speedup 1.0000x reference)
//
#include <hip/hip_runtime.h>

#define DEPTH_LIMIT 10
typedef float f32x4 __attribute__((ext_vector_type(4)));

// ---------------- Pre-pass: collapse first 6 levels into a Morton LUT -------
// lut[m] for m in [0, 8^6): traverse the child table along Morton path m.
// >=0 : index of the level-6 internal node reached after 6 descents
// <0  : ~leaf_flat_id (a leaf was hit before level 6 -- generic trees only)
__global__ __launch_bounds__(256) void build_lut_kernel(
    const int* __restrict__ child, int* __restrict__ lut)
{
    const int m = blockIdx.x * blockDim.x + threadIdx.x;   // 0..262143
    int u = 0;
    int res = 0;
    bool early = false;
    #pragma unroll
    for (int l = 0; l < 6; ++l) {
        int ci = (m >> (3 * (5 - l))) & 7;
        int flat = (u << 3) | ci;
        int c = child[flat];
        if (c == 0) { res = ~flat; early = true; break; }
        u += c;
    }
    lut[m] = early ? res : u;
}

// Generic continuation for trees deeper than 7 levels (never taken on a
// fully-refined depth-7 tree; exec-mask-skipped).
__device__ int deep_continue(const int* __restrict__ child, int u,
                             float fx, float fy, float fz)
{
    int leaf = 0;
    for (int l = 7; l < DEPTH_LIMIT; ++l) {
        fx *= 2.0f; fy *= 2.0f; fz *= 2.0f;
        int cx = min(max((int)fx, 0), 1);
        int cy = min(max((int)fy, 0), 1);
        int cz = min(max((int)fz, 0), 1);
        fx -= (float)cx; fy -= (float)cy; fz -= (float)cz;
        int fl = (u << 3) | (cx << 2) | (cy << 1) | cz;
        int cc = child[fl];
        if (cc == 0) { leaf = fl; break; }
        u += cc;
    }
    return leaf;
}

// ---------------- Main: 2 points/thread, 3-deep gather chain ----------------
__global__ __launch_bounds__(256) void adtree_main_kernel(
    const float* __restrict__ data,      // [n_internal*8, 32]
    const int*   __restrict__ child,     // [n_internal*8]
    const int*   __restrict__ lut,       // [8^6]
    const float* __restrict__ points,    // [P, 3]
    const float* __restrict__ offset,
    const float* __restrict__ invradius,
    float*       __restrict__ out,       // [P*32] data, then [P] ids (float)
    int P)
{
    const int lane   = threadIdx.x & 63;
    const int waveId = (blockIdx.x * blockDim.x + threadIdx.x) >> 6;
    const long base  = (long)waveId * 128;
    if (base >= P) return;               // P % 128 == 0

    const float ox = offset[0], oy = offset[1], oz = offset[2];
    const float ix = invradius[0], iy = invradius[1], iz = invradius[2];
    const float HI = 1.0f - 1e-6f;

    const int idx0 = (int)base + lane;
    const int idx1 = (int)base + 64 + lane;

    float px0 = fminf(fmaxf(ox + points[(size_t)idx0 * 3 + 0] * ix, 0.0f), HI);
    float py0 = fminf(fmaxf(oy + points[(size_t)idx0 * 3 + 1] * iy, 0.0f), HI);
    float pz0 = fminf(fmaxf(oz + points[(size_t)idx0 * 3 + 2] * iz, 0.0f), HI);
    float px1 = fminf(fmaxf(ox + points[(size_t)idx1 * 3 + 0] * ix, 0.0f), HI);
    float py1 = fminf(fmaxf(oy + points[(size_t)idx1 * 3 + 1] * iy, 0.0f), HI);
    float pz1 = fminf(fmaxf(oz + points[(size_t)idx1 * 3 + 2] * iz, 0.0f), HI);

    // 7 binary digits per axis (exactly the p*2-cell recurrence, closed form)
    int ex0 = (int)(px0 * 128.0f), ey0 = (int)(py0 * 128.0f), ez0 = (int)(pz0 * 128.0f);
    int ex1 = (int)(px1 * 128.0f), ey1 = (int)(py1 * 128.0f), ez1 = (int)(pz1 * 128.0f);

    int m0 = 0, m1 = 0;
    #pragma unroll
    for (int l = 0; l < 6; ++l) {
        int b = 6 - l;
        m0 = (m0 << 3) | (((ex0 >> b) & 1) << 2) | (((ey0 >> b) & 1) << 1) | ((ez0 >> b) & 1);
        m1 = (m1 << 3) | (((ex1 >> b) & 1) << 2) | (((ey1 >> b) & 1) << 1) | ((ez1 >> b) & 1);
    }
    const int ci0 = ((ex0 & 1) << 2) | ((ey0 & 1) << 1) | (ez0 & 1);
    const int ci1 = ((ex1 & 1) << 2) | ((ey1 & 1) << 1) | (ez1 & 1);

    // chain level 1: LUT (both issue together)
    const int lv0 = lut[m0];
    const int lv1 = lut[m1];

    // chain level 2: leaf check in child (guard keeps OOB-safe on generic trees)
    const int flat0 = ((lv0 < 0 ? 0 : lv0) << 3) | ci0;
    const int flat1 = ((lv1 < 0 ? 0 : lv1) << 3) | ci1;
    const int c0 = child[flat0];
    const int c1 = child[flat1];

    int leaf0, leaf1;
    if (lv0 < 0)       leaf0 = ~lv0;
    else if (c0 == 0)  leaf0 = flat0;
    else               leaf0 = deep_continue(child, lv0 + c0,
                              px0 * 128.0f - (float)ex0, py0 * 128.0f - (float)ey0,
                              pz0 * 128.0f - (float)ez0);
    if (lv1 < 0)       leaf1 = ~lv1;
    else if (c1 == 0)  leaf1 = flat1;
    else               leaf1 = deep_continue(child, lv1 + c1,
                              px1 * 128.0f - (float)ex1, py1 * 128.0f - (float)ey1,
                              pz1 * 128.0f - (float)ez1);

    // id outputs (float32-compared; ids < 2^24 so exact)
    __builtin_nontemporal_store((float)leaf0, out + (size_t)P * 32 + idx0);
    __builtin_nontemporal_store((float)leaf1, out + (size_t)P * 32 + idx1);

    // chain level 3: cooperative leaf-row copy (8 lanes/point, 16B/lane,
    // contiguous 1KB nt-stores per iteration)
    const size_t obase = (size_t)base * 32;
    #pragma unroll
    for (int r = 0; r < 16; ++r) {
        int j  = (r << 3) | (lane >> 3);
        int lf = __shfl(r < 8 ? leaf0 : leaf1, j & 63, 64);
        f32x4 v = *reinterpret_cast<const f32x4*>(
            data + (size_t)lf * 32 + ((lane & 7) << 2));
        __builtin_nontemporal_store(
            v, reinterpret_cast<f32x4*>(out + obase + (size_t)r * 256) + lane);
    }
}

// ---------------- Fallback (R2 kernel) if ws_size < 1MB ---------------------
__global__ __launch_bounds__(256) void adtree_fallback_kernel(
    const float* __restrict__ data, const int* __restrict__ child,
    const float* __restrict__ points, const float* __restrict__ offset,
    const float* __restrict__ invradius, float* __restrict__ out, int P)
{
    const int lane   = threadIdx.x & 63;
    const int waveId = (blockIdx.x * blockDim.x + threadIdx.x) >> 6;
    const long base  = (long)waveId * 128;
    if (base >= P) return;

    const float ox = offset[0], oy = offset[1], oz = offset[2];
    const float ix = invradius[0], iy = invradius[1], iz = invradius[2];
    const float HI = 1.0f - 1e-6f;
    const int idx0 = (int)base + lane, idx1 = (int)base + 64 + lane;

    float px0 = fminf(fmaxf(ox + points[(size_t)idx0 * 3 + 0] * ix, 0.0f), HI);
    float py0 = fminf(fmaxf(oy + points[(size_t)idx0 * 3 + 1] * iy, 0.0f), HI);
    float pz0 = fminf(fmaxf(oz + points[(size_t)idx0 * 3 + 2] * iz, 0.0f), HI);
    float px1 = fminf(fmaxf(ox + points[(size_t)idx1 * 3 + 0] * ix, 0.0f), HI);
    float py1 = fminf(fmaxf(oy + points[(size_t)idx1 * 3 + 1] * iy, 0.0f), HI);
    float pz1 = fminf(fmaxf(oz + points[(size_t)idx1 * 3 + 2] * iz, 0.0f), HI);

    int u0 = 0, u1 = 0, leaf0 = 0, leaf1 = 0;
    bool d0 = false, d1 = false;
    #pragma unroll 1
    for (int it = 0; it < DEPTH_LIMIT; ++it) {
        int cx0 = min(max((int)(px0 * 2.0f), 0), 1);
        int cy0 = min(max((int)(py0 * 2.0f), 0), 1);
        int cz0 = min(max((int)(pz0 * 2.0f), 0), 1);
        int flat0 = (u0 << 3) | (cx0 << 2) | (cy0 << 1) | cz0;
        int cx1 = min(max((int)(px1 * 2.0f), 0), 1);
        int cy1 = min(max((int)(py1 * 2.0f), 0), 1);
        int cz1 = min(max((int)(pz1 * 2.0f), 0), 1);
        int flat1 = (u1 << 3) | (cx1 << 2) | (cy1 << 1) | cz1;
        int c0 = child[flat0];
        int c1 = child[flat1];
        bool il0 = (c0 == 0) & !d0;
        bool il1 = (c1 == 0) & !d1;
        leaf0 = il0 ? flat0 : leaf0;
        leaf1 = il1 ? flat1 : leaf1;
        d0 |= il0; d1 |= il1;
        if (!d0) { u0 += c0; px0 = px0*2.0f-(float)cx0; py0 = py0*2.0f-(float)cy0; pz0 = pz0*2.0f-(float)cz0; }
        if (!d1) { u1 += c1; px1 = px1*2.0f-(float)cx1; py1 = py1*2.0f-(float)cy1; pz1 = pz1*2.0f-(float)cz1; }
        if (__all(d0 && d1)) break;
    }
    __builtin_nontemporal_store((float)leaf0, out + (size_t)P * 32 + idx0);
    __builtin_nontemporal_store((float)leaf1, out + (size_t)P * 32 + idx1);
    const size_t obase = (size_t)base * 32;
    #pragma unroll
    for (int r = 0; r < 16; ++r) {
        int j  = (r << 3) | (lane >> 3);
        int lf = __shfl(r < 8 ? leaf0 : leaf1, j & 63, 64);
        f32x4 v = *reinterpret_cast<const f32x4*>(
            data + (size_t)lf * 32 + ((lane & 7) << 2));
        __builtin_nontemporal_store(
            v, reinterpret_cast<f32x4*>(out + obase + (size_t)r * 256) + lane);
    }
}

extern "C" void kernel_launch(void* const* d_in, const int* in_sizes, int n_in,
                              void* d_out, int out_size, void* d_ws, size_t ws_size,
                              hipStream_t stream) {
    const float* data      = (const float*)d_in[0];
    const int*   child     = (const int*)d_in[1];
    const float* points    = (const float*)d_in[2];
    const float* offset    = (const float*)d_in[3];
    const float* invradius = (const float*)d_in[4];
    float* out = (float*)d_out;

    const int P = in_sizes[2] / 3;                 // 2,000,000
    const int LUT_N = 262144;                      // 8^6
    const int block = 256;

    if (ws_size >= (size_t)LUT_N * sizeof(int)) {
        int* lut = (int*)d_ws;
        hipLaunchKernelGGL(build_lut_kernel, dim3(LUT_N / block), dim3(block),
                           0, stream, child, lut);
        const int threads = ((P + 127) / 128) * 64;
        const int grid = (threads + block - 1) / block;
        hipLaunchKernelGGL(adtree_main_kernel, dim3(grid), dim3(block), 0, stream,
                           data, child, lut, points, offset, invradius, out, P);
    } else {
        const int threads = ((P + 127) / 128) * 64;
        const int grid = (threads + block - 1) / block;
        hipLaunchKernelGGL(adtree_fallback_kernel, dim3(grid), dim3(block), 0, stream,
                           data, child, points, offset, invradius, out, P);
    }
}

// Round 4
// 106.270 us; speedup vs baseline: 1.1963x; 1.1963x over previous
//
#include <hip/hip_runtime.h>

#define DEPTH_LIMIT 10
typedef float f32x4 __attribute__((ext_vector_type(4)));

#define ALL_LEAF_BIT (1 << 30)

// ---------------- Pre-pass: collapse first 6 levels into a Morton LUT -------
// lut[m] for m in [0, 8^6):
//   >= 0 : node index u of the level-6 internal node reached after 6 descents,
//          with bit30 set iff ALL 8 children of u are leaves (lets the main
//          kernel skip the child[] leaf-check gather entirely).
//   <  0 : ~leaf_flat_id (a leaf was hit before level 6 -- generic trees).
__global__ __launch_bounds__(256) void build_lut_kernel(
    const int* __restrict__ child, int* __restrict__ lut)
{
    const int m = blockIdx.x * blockDim.x + threadIdx.x;   // 0..262143
    int u = 0;
    int res = 0;
    bool early = false;
    #pragma unroll
    for (int l = 0; l < 6; ++l) {
        int ci = (m >> (3 * (5 - l))) & 7;
        int flat = (u << 3) | ci;
        int c = child[flat];
        if (c == 0) { res = ~flat; early = true; break; }
        u += c;
    }
    if (!early) {
        bool all_leaf = true;
        #pragma unroll
        for (int k = 0; k < 8; ++k) all_leaf &= (child[(u << 3) | k] == 0);
        res = u | (all_leaf ? ALL_LEAF_BIT : 0);
    }
    lut[m] = res;
}

// Generic continuation for trees deeper than 7 levels (never taken on a
// fully-refined depth-7 tree; exec-mask-skipped).
__device__ int deep_continue(const int* __restrict__ child, int u,
                             float fx, float fy, float fz)
{
    int leaf = 0;
    for (int l = 7; l < DEPTH_LIMIT; ++l) {
        fx *= 2.0f; fy *= 2.0f; fz *= 2.0f;
        int cx = min(max((int)fx, 0), 1);
        int cy = min(max((int)fy, 0), 1);
        int cz = min(max((int)fz, 0), 1);
        fx -= (float)cx; fy -= (float)cy; fz -= (float)cz;
        int fl = (u << 3) | (cx << 2) | (cy << 1) | cz;
        int cc = child[fl];
        if (cc == 0) { leaf = fl; break; }
        u += cc;
    }
    return leaf;
}

__device__ __forceinline__ int resolve_leaf(const int* __restrict__ child,
                                            int lv, int ci,
                                            float fx, float fy, float fz)
{
    if (lv < 0) return ~lv;                       // early leaf (generic trees)
    const int u = lv & ~ALL_LEAF_BIT;
    const int flat = (u << 3) | ci;
    if (lv & ALL_LEAF_BIT) return flat;           // common case: no gather
    const int c = child[flat];                    // generic: leaf-check gather
    if (c == 0) return flat;
    return deep_continue(child, u + c, fx, fy, fz);
}

// ---------------- Main: 2 points/thread, LUT gather + row gather ------------
__global__ __launch_bounds__(256) void adtree_main_kernel(
    const float* __restrict__ data,      // [n_internal*8, 32]
    const int*   __restrict__ child,     // [n_internal*8]
    const int*   __restrict__ lut,       // [8^6]
    const float* __restrict__ points,    // [P, 3]
    const float* __restrict__ offset,
    const float* __restrict__ invradius,
    float*       __restrict__ out,       // [P*32] data, then [P] ids (float)
    int P)
{
    const int lane   = threadIdx.x & 63;
    const int waveId = (blockIdx.x * blockDim.x + threadIdx.x) >> 6;
    const long base  = (long)waveId * 128;
    if (base >= P) return;               // P % 128 == 0

    const float ox = offset[0], oy = offset[1], oz = offset[2];
    const float ix = invradius[0], iy = invradius[1], iz = invradius[2];
    const float HI = 1.0f - 1e-6f;

    const int idx0 = (int)base + lane;
    const int idx1 = (int)base + 64 + lane;

    float px0 = fminf(fmaxf(ox + points[(size_t)idx0 * 3 + 0] * ix, 0.0f), HI);
    float py0 = fminf(fmaxf(oy + points[(size_t)idx0 * 3 + 1] * iy, 0.0f), HI);
    float pz0 = fminf(fmaxf(oz + points[(size_t)idx0 * 3 + 2] * iz, 0.0f), HI);
    float px1 = fminf(fmaxf(ox + points[(size_t)idx1 * 3 + 0] * ix, 0.0f), HI);
    float py1 = fminf(fmaxf(oy + points[(size_t)idx1 * 3 + 1] * iy, 0.0f), HI);
    float pz1 = fminf(fmaxf(oz + points[(size_t)idx1 * 3 + 2] * iz, 0.0f), HI);

    // 7 binary digits per axis (exact closed form of the p*2-cell recurrence)
    int ex0 = (int)(px0 * 128.0f), ey0 = (int)(py0 * 128.0f), ez0 = (int)(pz0 * 128.0f);
    int ex1 = (int)(px1 * 128.0f), ey1 = (int)(py1 * 128.0f), ez1 = (int)(pz1 * 128.0f);

    int m0 = 0, m1 = 0;
    #pragma unroll
    for (int l = 0; l < 6; ++l) {
        int b = 6 - l;
        m0 = (m0 << 3) | (((ex0 >> b) & 1) << 2) | (((ey0 >> b) & 1) << 1) | ((ez0 >> b) & 1);
        m1 = (m1 << 3) | (((ex1 >> b) & 1) << 2) | (((ey1 >> b) & 1) << 1) | ((ez1 >> b) & 1);
    }
    const int ci0 = ((ex0 & 1) << 2) | ((ey0 & 1) << 1) | (ez0 & 1);
    const int ci1 = ((ex1 & 1) << 2) | ((ey1 & 1) << 1) | (ez1 & 1);

    // LUT gathers (1MB, L2-resident; both issue together)
    const int lv0 = lut[m0];
    const int lv1 = lut[m1];

    const int leaf0 = resolve_leaf(child, lv0, ci0,
        px0 * 128.0f - (float)ex0, py0 * 128.0f - (float)ey0, pz0 * 128.0f - (float)ez0);
    const int leaf1 = resolve_leaf(child, lv1, ci1,
        px1 * 128.0f - (float)ex1, py1 * 128.0f - (float)ey1, pz1 * 128.0f - (float)ez1);

    // id outputs (float32-compared; ids < 2^24 so exact)
    __builtin_nontemporal_store((float)leaf0, out + (size_t)P * 32 + idx0);
    __builtin_nontemporal_store((float)leaf1, out + (size_t)P * 32 + idx1);

    // Cooperative leaf-row copy: 8 lanes/point, 16B/lane, contiguous 1KB
    // nt-stores. Row loads are NON-TEMPORAL: once-touched random lines must
    // not evict LUT (L2) or repeat-rows (L3).
    const size_t obase = (size_t)base * 32;
    #pragma unroll
    for (int r = 0; r < 16; ++r) {
        int j  = (r << 3) | (lane >> 3);
        int lf = __shfl(r < 8 ? leaf0 : leaf1, j & 63, 64);
        f32x4 v = __builtin_nontemporal_load(
            reinterpret_cast<const f32x4*>(data + (size_t)lf * 32) + (lane & 7));
        __builtin_nontemporal_store(
            v, reinterpret_cast<f32x4*>(out + obase + (size_t)r * 256) + lane);
    }
}

// ---------------- Fallback (R2 kernel) if ws_size < 1MB ---------------------
__global__ __launch_bounds__(256) void adtree_fallback_kernel(
    const float* __restrict__ data, const int* __restrict__ child,
    const float* __restrict__ points, const float* __restrict__ offset,
    const float* __restrict__ invradius, float* __restrict__ out, int P)
{
    const int lane   = threadIdx.x & 63;
    const int waveId = (blockIdx.x * blockDim.x + threadIdx.x) >> 6;
    const long base  = (long)waveId * 128;
    if (base >= P) return;

    const float ox = offset[0], oy = offset[1], oz = offset[2];
    const float ix = invradius[0], iy = invradius[1], iz = invradius[2];
    const float HI = 1.0f - 1e-6f;
    const int idx0 = (int)base + lane, idx1 = (int)base + 64 + lane;

    float px0 = fminf(fmaxf(ox + points[(size_t)idx0 * 3 + 0] * ix, 0.0f), HI);
    float py0 = fminf(fmaxf(oy + points[(size_t)idx0 * 3 + 1] * iy, 0.0f), HI);
    float pz0 = fminf(fmaxf(oz + points[(size_t)idx0 * 3 + 2] * iz, 0.0f), HI);
    float px1 = fminf(fmaxf(ox + points[(size_t)idx1 * 3 + 0] * ix, 0.0f), HI);
    float py1 = fminf(fmaxf(oy + points[(size_t)idx1 * 3 + 1] * iy, 0.0f), HI);
    float pz1 = fminf(fmaxf(oz + points[(size_t)idx1 * 3 + 2] * iz, 0.0f), HI);

    int u0 = 0, u1 = 0, leaf0 = 0, leaf1 = 0;
    bool d0 = false, d1 = false;
    #pragma unroll 1
    for (int it = 0; it < DEPTH_LIMIT; ++it) {
        int cx0 = min(max((int)(px0 * 2.0f), 0), 1);
        int cy0 = min(max((int)(py0 * 2.0f), 0), 1);
        int cz0 = min(max((int)(pz0 * 2.0f), 0), 1);
        int flat0 = (u0 << 3) | (cx0 << 2) | (cy0 << 1) | cz0;
        int cx1 = min(max((int)(px1 * 2.0f), 0), 1);
        int cy1 = min(max((int)(py1 * 2.0f), 0), 1);
        int cz1 = min(max((int)(pz1 * 2.0f), 0), 1);
        int flat1 = (u1 << 3) | (cx1 << 2) | (cy1 << 1) | cz1;
        int c0 = child[flat0];
        int c1 = child[flat1];
        bool il0 = (c0 == 0) & !d0;
        bool il1 = (c1 == 0) & !d1;
        leaf0 = il0 ? flat0 : leaf0;
        leaf1 = il1 ? flat1 : leaf1;
        d0 |= il0; d1 |= il1;
        if (!d0) { u0 += c0; px0 = px0*2.0f-(float)cx0; py0 = py0*2.0f-(float)cy0; pz0 = pz0*2.0f-(float)cz0; }
        if (!d1) { u1 += c1; px1 = px1*2.0f-(float)cx1; py1 = py1*2.0f-(float)cy1; pz1 = pz1*2.0f-(float)cz1; }
        if (__all(d0 && d1)) break;
    }
    __builtin_nontemporal_store((float)leaf0, out + (size_t)P * 32 + idx0);
    __builtin_nontemporal_store((float)leaf1, out + (size_t)P * 32 + idx1);
    const size_t obase = (size_t)base * 32;
    #pragma unroll
    for (int r = 0; r < 16; ++r) {
        int j  = (r << 3) | (lane >> 3);
        int lf = __shfl(r < 8 ? leaf0 : leaf1, j & 63, 64);
        f32x4 v = *reinterpret_cast<const f32x4*>(
            data + (size_t)lf * 32 + ((lane & 7) << 2));
        __builtin_nontemporal_store(
            v, reinterpret_cast<f32x4*>(out + obase + (size_t)r * 256) + lane);
    }
}

extern "C" void kernel_launch(void* const* d_in, const int* in_sizes, int n_in,
                              void* d_out, int out_size, void* d_ws, size_t ws_size,
                              hipStream_t stream) {
    const float* data      = (const float*)d_in[0];
    const int*   child     = (const int*)d_in[1];
    const float* points    = (const float*)d_in[2];
    const float* offset    = (const float*)d_in[3];
    const float* invradius = (const float*)d_in[4];
    float* out = (float*)d_out;

    const int P = in_sizes[2] / 3;                 // 2,000,000
    const int LUT_N = 262144;                      // 8^6
    const int block = 256;

    if (ws_size >= (size_t)LUT_N * sizeof(int)) {
        int* lut = (int*)d_ws;
        hipLaunchKernelGGL(build_lut_kernel, dim3(LUT_N / block), dim3(block),
                           0, stream, child, lut);
        const int threads = ((P + 127) / 128) * 64;
        const int grid = (threads + block - 1) / block;
        hipLaunchKernelGGL(adtree_main_kernel, dim3(grid), dim3(block), 0, stream,
                           data, child, lut, points, offset, invradius, out, P);
    } else {
        const int threads = ((P + 127) / 128) * 64;
        const int grid = (threads + block - 1) / block;
        hipLaunchKernelGGL(adtree_fallback_kernel, dim3(grid), dim3(block), 0, stream,
                           data, child, points, offset, invradius, out, P);
    }
}

// Round 5
// 95.736 us; speedup vs baseline: 1.3279x; 1.1100x over previous
//
#include <hip/hip_runtime.h>

#define DEPTH_LIMIT 10
typedef float f32x4 __attribute__((ext_vector_type(4)));

#define ALL_LEAF_BIT (1 << 30)

// ---------------- Pre-pass: collapse first 6 levels into a Morton LUT -------
// lut[m] for m in [0, 8^6):
//   >= 0 : node index u of the level-6 internal node reached after 6 descents,
//          with bit30 set iff ALL 8 children of u are leaves (lets the main
//          kernel skip the child[] leaf-check gather entirely).
//   <  0 : ~leaf_flat_id (a leaf was hit before level 6 -- generic trees).
__global__ __launch_bounds__(256) void build_lut_kernel(
    const int* __restrict__ child, int* __restrict__ lut)
{
    const int m = blockIdx.x * blockDim.x + threadIdx.x;   // 0..262143
    int u = 0;
    int res = 0;
    bool early = false;
    #pragma unroll
    for (int l = 0; l < 6; ++l) {
        int ci = (m >> (3 * (5 - l))) & 7;
        int flat = (u << 3) | ci;
        int c = child[flat];
        if (c == 0) { res = ~flat; early = true; break; }
        u += c;
    }
    if (!early) {
        bool all_leaf = true;
        #pragma unroll
        for (int k = 0; k < 8; ++k) all_leaf &= (child[(u << 3) | k] == 0);
        res = u | (all_leaf ? ALL_LEAF_BIT : 0);
    }
    lut[m] = res;
}

// Generic continuation for trees deeper than 7 levels (never taken on a
// fully-refined depth-7 tree; exec-mask-skipped).
__device__ int deep_continue(const int* __restrict__ child, int u,
                             float fx, float fy, float fz)
{
    int leaf = 0;
    for (int l = 7; l < DEPTH_LIMIT; ++l) {
        fx *= 2.0f; fy *= 2.0f; fz *= 2.0f;
        int cx = min(max((int)fx, 0), 1);
        int cy = min(max((int)fy, 0), 1);
        int cz = min(max((int)fz, 0), 1);
        fx -= (float)cx; fy -= (float)cy; fz -= (float)cz;
        int fl = (u << 3) | (cx << 2) | (cy << 1) | cz;
        int cc = child[fl];
        if (cc == 0) { leaf = fl; break; }
        u += cc;
    }
    return leaf;
}

__device__ __forceinline__ int resolve_leaf(const int* __restrict__ child,
                                            int lv, int ci,
                                            float fx, float fy, float fz)
{
    if (lv < 0) return ~lv;                       // early leaf (generic trees)
    const int u = lv & ~ALL_LEAF_BIT;
    const int flat = (u << 3) | ci;
    if (lv & ALL_LEAF_BIT) return flat;           // common case: no gather
    const int c = child[flat];                    // generic: leaf-check gather
    if (c == 0) return flat;
    return deep_continue(child, u + c, fx, fy, fz);
}

// ---------------- Main: 2 points/thread, LUT gather + row gather ------------
__global__ __launch_bounds__(256) void adtree_main_kernel(
    const float* __restrict__ data,      // [n_internal*8, 32]
    const int*   __restrict__ child,     // [n_internal*8]
    const int*   __restrict__ lut,       // [8^6]
    const float* __restrict__ points,    // [P, 3]
    const float* __restrict__ offset,
    const float* __restrict__ invradius,
    float*       __restrict__ out,       // [P*32] data, then [P] ids (float)
    int P)
{
    const int lane   = threadIdx.x & 63;
    const int waveId = (blockIdx.x * blockDim.x + threadIdx.x) >> 6;
    const long base  = (long)waveId * 128;
    if (base >= P) return;               // P % 128 == 0

    const float ox = offset[0], oy = offset[1], oz = offset[2];
    const float ix = invradius[0], iy = invradius[1], iz = invradius[2];
    const float HI = 1.0f - 1e-6f;

    const int idx0 = (int)base + lane;
    const int idx1 = (int)base + 64 + lane;

    float px0 = fminf(fmaxf(ox + points[(size_t)idx0 * 3 + 0] * ix, 0.0f), HI);
    float py0 = fminf(fmaxf(oy + points[(size_t)idx0 * 3 + 1] * iy, 0.0f), HI);
    float pz0 = fminf(fmaxf(oz + points[(size_t)idx0 * 3 + 2] * iz, 0.0f), HI);
    float px1 = fminf(fmaxf(ox + points[(size_t)idx1 * 3 + 0] * ix, 0.0f), HI);
    float py1 = fminf(fmaxf(oy + points[(size_t)idx1 * 3 + 1] * iy, 0.0f), HI);
    float pz1 = fminf(fmaxf(oz + points[(size_t)idx1 * 3 + 2] * iz, 0.0f), HI);

    // 7 binary digits per axis (exact closed form of the p*2-cell recurrence)
    int ex0 = (int)(px0 * 128.0f), ey0 = (int)(py0 * 128.0f), ez0 = (int)(pz0 * 128.0f);
    int ex1 = (int)(px1 * 128.0f), ey1 = (int)(py1 * 128.0f), ez1 = (int)(pz1 * 128.0f);

    int m0 = 0, m1 = 0;
    #pragma unroll
    for (int l = 0; l < 6; ++l) {
        int b = 6 - l;
        m0 = (m0 << 3) | (((ex0 >> b) & 1) << 2) | (((ey0 >> b) & 1) << 1) | ((ez0 >> b) & 1);
        m1 = (m1 << 3) | (((ex1 >> b) & 1) << 2) | (((ey1 >> b) & 1) << 1) | ((ez1 >> b) & 1);
    }
    const int ci0 = ((ex0 & 1) << 2) | ((ey0 & 1) << 1) | (ez0 & 1);
    const int ci1 = ((ex1 & 1) << 2) | ((ey1 & 1) << 1) | (ez1 & 1);

    // LUT gathers (1MB, L2-resident; both issue together)
    const int lv0 = lut[m0];
    const int lv1 = lut[m1];

    const int leaf0 = resolve_leaf(child, lv0, ci0,
        px0 * 128.0f - (float)ex0, py0 * 128.0f - (float)ey0, pz0 * 128.0f - (float)ez0);
    const int leaf1 = resolve_leaf(child, lv1, ci1,
        px1 * 128.0f - (float)ex1, py1 * 128.0f - (float)ey1, pz1 * 128.0f - (float)ez1);

    // id outputs (float32-compared; ids < 2^24 so exact)
    __builtin_nontemporal_store((float)leaf0, out + (size_t)P * 32 + idx0);
    __builtin_nontemporal_store((float)leaf1, out + (size_t)P * 32 + idx1);

    // Cooperative leaf-row copy: 8 lanes/point, 16B/lane, contiguous 1KB
    // nt-stores. Row loads are CACHED (vs R4's nt): the touched row set
    // (~165MB) + points + child + LUT fits in the 256MB L3, so within-replay
    // repeats (~35% of row reads) and cross-replay residency turn HBM reads
    // into L3 hits. Stores stay nt so the 264MB output stream doesn't evict.
    const size_t obase = (size_t)base * 32;
    #pragma unroll
    for (int r = 0; r < 16; ++r) {
        int j  = (r << 3) | (lane >> 3);
        int lf = __shfl(r < 8 ? leaf0 : leaf1, j & 63, 64);
        f32x4 v = *(reinterpret_cast<const f32x4*>(data + (size_t)lf * 32) + (lane & 7));
        __builtin_nontemporal_store(
            v, reinterpret_cast<f32x4*>(out + obase + (size_t)r * 256) + lane);
    }
}

// ---------------- Fallback (R2 kernel) if ws_size < 1MB ---------------------
__global__ __launch_bounds__(256) void adtree_fallback_kernel(
    const float* __restrict__ data, const int* __restrict__ child,
    const float* __restrict__ points, const float* __restrict__ offset,
    const float* __restrict__ invradius, float* __restrict__ out, int P)
{
    const int lane   = threadIdx.x & 63;
    const int waveId = (blockIdx.x * blockDim.x + threadIdx.x) >> 6;
    const long base  = (long)waveId * 128;
    if (base >= P) return;

    const float ox = offset[0], oy = offset[1], oz = offset[2];
    const float ix = invradius[0], iy = invradius[1], iz = invradius[2];
    const float HI = 1.0f - 1e-6f;
    const int idx0 = (int)base + lane, idx1 = (int)base + 64 + lane;

    float px0 = fminf(fmaxf(ox + points[(size_t)idx0 * 3 + 0] * ix, 0.0f), HI);
    float py0 = fminf(fmaxf(oy + points[(size_t)idx0 * 3 + 1] * iy, 0.0f), HI);
    float pz0 = fminf(fmaxf(oz + points[(size_t)idx0 * 3 + 2] * iz, 0.0f), HI);
    float px1 = fminf(fmaxf(ox + points[(size_t)idx1 * 3 + 0] * ix, 0.0f), HI);
    float py1 = fminf(fmaxf(oy + points[(size_t)idx1 * 3 + 1] * iy, 0.0f), HI);
    float pz1 = fminf(fmaxf(oz + points[(size_t)idx1 * 3 + 2] * iz, 0.0f), HI);

    int u0 = 0, u1 = 0, leaf0 = 0, leaf1 = 0;
    bool d0 = false, d1 = false;
    #pragma unroll 1
    for (int it = 0; it < DEPTH_LIMIT; ++it) {
        int cx0 = min(max((int)(px0 * 2.0f), 0), 1);
        int cy0 = min(max((int)(py0 * 2.0f), 0), 1);
        int cz0 = min(max((int)(pz0 * 2.0f), 0), 1);
        int flat0 = (u0 << 3) | (cx0 << 2) | (cy0 << 1) | cz0;
        int cx1 = min(max((int)(px1 * 2.0f), 0), 1);
        int cy1 = min(max((int)(py1 * 2.0f), 0), 1);
        int cz1 = min(max((int)(pz1 * 2.0f), 0), 1);
        int flat1 = (u1 << 3) | (cx1 << 2) | (cy1 << 1) | cz1;
        int c0 = child[flat0];
        int c1 = child[flat1];
        bool il0 = (c0 == 0) & !d0;
        bool il1 = (c1 == 0) & !d1;
        leaf0 = il0 ? flat0 : leaf0;
        leaf1 = il1 ? flat1 : leaf1;
        d0 |= il0; d1 |= il1;
        if (!d0) { u0 += c0; px0 = px0*2.0f-(float)cx0; py0 = py0*2.0f-(float)cy0; pz0 = pz0*2.0f-(float)cz0; }
        if (!d1) { u1 += c1; px1 = px1*2.0f-(float)cx1; py1 = py1*2.0f-(float)cy1; pz1 = pz1*2.0f-(float)cz1; }
        if (__all(d0 && d1)) break;
    }
    __builtin_nontemporal_store((float)leaf0, out + (size_t)P * 32 + idx0);
    __builtin_nontemporal_store((float)leaf1, out + (size_t)P * 32 + idx1);
    const size_t obase = (size_t)base * 32;
    #pragma unroll
    for (int r = 0; r < 16; ++r) {
        int j  = (r << 3) | (lane >> 3);
        int lf = __shfl(r < 8 ? leaf0 : leaf1, j & 63, 64);
        f32x4 v = *reinterpret_cast<const f32x4*>(
            data + (size_t)lf * 32 + ((lane & 7) << 2));
        __builtin_nontemporal_store(
            v, reinterpret_cast<f32x4*>(out + obase + (size_t)r * 256) + lane);
    }
}

extern "C" void kernel_launch(void* const* d_in, const int* in_sizes, int n_in,
                              void* d_out, int out_size, void* d_ws, size_t ws_size,
                              hipStream_t stream) {
    const float* data      = (const float*)d_in[0];
    const int*   child     = (const int*)d_in[1];
    const float* points    = (const float*)d_in[2];
    const float* offset    = (const float*)d_in[3];
    const float* invradius = (const float*)d_in[4];
    float* out = (float*)d_out;

    const int P = in_sizes[2] / 3;                 // 2,000,000
    const int LUT_N = 262144;                      // 8^6
    const int block = 256;

    if (ws_size >= (size_t)LUT_N * sizeof(int)) {
        int* lut = (int*)d_ws;
        hipLaunchKernelGGL(build_lut_kernel, dim3(LUT_N / block), dim3(block),
                           0, stream, child, lut);
        const int threads = ((P + 127) / 128) * 64;
        const int grid = (threads + block - 1) / block;
        hipLaunchKernelGGL(adtree_main_kernel, dim3(grid), dim3(block), 0, stream,
                           data, child, lut, points, offset, invradius, out, P);
    } else {
        const int threads = ((P + 127) / 128) * 64;
        const int grid = (threads + block - 1) / block;
        hipLaunchKernelGGL(adtree_fallback_kernel, dim3(grid), dim3(block), 0, stream,
                           data, child, points, offset, invradius, out, P);
    }
}